// Round 2
// baseline (3695.825 us; speedup 1.0000x reference)
//
#include <hip/hip_runtime.h>
#include <stdint.h>

// Problem constants (fixed by setup_inputs)
#define PN     512
#define NFREE  50000
#define NCND   100000
#define NNODE  100512
#define NEDGE  300000
#define KK     10
#define NLOOP  5
#define EPSV   1e-5f

#define NPART  8
#define CPP    12500          // candidates per partition (NCND/NPART)
#define KITER  13             // ceil(CPP / (256*4))

#define HSIZE  (1u<<20)
#define HMASK  (HSIZE-1)
#define E0CAP  4096
#define EMPTYK 0xFFFFFFFFFFFFFFFFull

// workspace layout (bytes) — total ~9.8 MB
#define OFF_HASH  ((size_t)0)
#define OFF_CPOS  (OFF_HASH + (size_t)HSIZE*8)
#define OFF_CSQ   (OFF_CPOS + (size_t)2*NCND*4)
#define OFF_SUMC  (OFF_CSQ + (size_t)NCND*4)
#define OFF_SUMC2 (OFF_SUMC + 128)
#define OFF_MEAN  (OFF_SUMC2 + 128)
#define OFF_RSTD  (OFF_MEAN + 128)
#define OFF_WCU   (OFF_RSTD + 128)
#define OFF_WCV   (OFF_WCU + 4096)
#define OFF_BU    (OFF_WCV + 4096)
#define OFF_BV    (OFF_BU + 128)
#define OFF_CPATH (OFF_BV + 128)
#define OFF_CFREE (OFF_CPATH + 128)
#define OFF_CCOL  (OFF_CFREE + 128)
#define OFF_PATH  (OFF_CCOL + 128)
#define OFF_UPATH (OFF_PATH + 4096)
#define OFF_VDST  (OFF_UPATH + 65536)
#define OFF_SBUF  (OFF_VDST + 65536)
#define OFF_E0S   (OFF_SBUF + 65536)
#define OFF_E0D   (OFF_E0S + (size_t)E0CAP*4)
#define OFF_DEG0  (OFF_E0D + (size_t)E0CAP*4)
#define OFF_E0C   (OFF_DEG0 + 2048)
#define OFF_KSRC  (OFF_E0C + 64)
#define OFF_KKEEP (OFF_KSRC + (size_t)PN*KK*4)
#define OFF_KPD   (OFF_KKEEP + (size_t)PN*KK*4)
#define OFF_KPI   (OFF_KPD + (size_t)PN*NPART*10*4)

#define WS_F(o)  ((float*)(ws + (o)))
#define WS_I(o)  ((int*)(ws + (o)))
#define WS_H(o)  ((unsigned long long*)(ws + (o)))

__device__ __forceinline__ bool lexless(float da, int ia, float db, int ib) {
  return (da < db) || (da == db && ia < ib);
}

__device__ __forceinline__ uint32_t hslot(unsigned long long key) {
  return (uint32_t)((key * 0x9E3779B97F4A7C15ull) >> 40) & HMASK;
}

#define INSERT10(d2v, jv)                                                  \
  if (lexless((d2v), (jv), bd[9], bi[9])) {                                \
    bool placed = false;                                                   \
    _Pragma("unroll")                                                      \
    for (int k = 9; k > 0; k--) {                                          \
      bool shift = !placed && lexless((d2v), (jv), bd[k-1], bi[k-1]);      \
      bool here  = !placed && !shift;                                      \
      if (here)       { bd[k] = (d2v); bi[k] = (jv); placed = true; }      \
      else if (shift) { bd[k] = bd[k-1]; bi[k] = bi[k-1]; }                \
    }                                                                      \
    if (!placed) { bd[0] = (d2v); bi[0] = (jv); }                          \
  }

// ---------------- setup kernels (once per launch) ----------------

__global__ __launch_bounds__(256) void k_init(char* __restrict__ ws,
                                              const float* __restrict__ path_in) {
  unsigned i = blockIdx.x * 256u + threadIdx.x;
  WS_H(OFF_HASH)[i] = EMPTYK;                 // grid sized exactly HSIZE
  if (i < 1024) WS_F(OFF_PATH)[i] = path_in[i];
  if (i < 512)  WS_I(OFF_DEG0)[i] = 0;
  if (i < 32) { WS_F(OFF_SUMC)[i] = 0.f; WS_F(OFF_SUMC2)[i] = 0.f; }
  if (i == 0)   *WS_I(OFF_E0C) = 0;
}

// candidate positions, squared norms, h1 feature sums (BN stats, cand part)
__global__ __launch_bounds__(256) void k_cand(char* __restrict__ ws,
    const float* __restrict__ freep, const float* __restrict__ collp,
    const float* __restrict__ ncw1, const float* __restrict__ ncb1) {
  __shared__ float ls[64];
  int tid = threadIdx.x;
  if (tid < 64) ls[tid] = 0.f;
  __syncthreads();
  int j = blockIdx.x * 256 + tid;
  float c0 = 0.f, c1 = 0.f;
  bool valid = (j < NCND);
  if (valid) {
    if (j < NFREE) { c0 = freep[2*j];          c1 = freep[2*j+1]; }
    else           { c0 = collp[2*(j-NFREE)];  c1 = collp[2*(j-NFREE)+1]; }
    WS_F(OFF_CPOS)[2*j] = c0; WS_F(OFF_CPOS)[2*j+1] = c1;
    WS_F(OFF_CSQ)[j] = c0*c0 + c1*c1;
  }
  for (int ff = 0; ff < 32; ff++) {
    int f = (tid + ff) & 31;                  // stagger → no LDS same-addr pileup
    if (valid) {
      float cls = (j < NFREE) ? (ncw1[96+f] + ncb1[f]) : (ncw1[128+f] + ncb1[f]);
      float h = fmaf(c1, ncw1[32+f], fmaf(c0, ncw1[f], cls));
      atomicAdd(&ls[f], h);
      atomicAdd(&ls[32+f], h*h);
    }
  }
  __syncthreads();
  if (tid < 32) {
    atomicAdd(&WS_F(OFF_SUMC)[tid],  ls[tid]);
    atomicAdd(&WS_F(OFF_SUMC2)[tid], ls[32+tid]);
  }
}

// combined weights: Wcu = ncW2·(W1a+W1b), Wcv = ncW2·(W1c−W1a), biases, class consts
__global__ __launch_bounds__(1024) void k_wprep(char* __restrict__ ws,
    const float* __restrict__ m0w1, const float* __restrict__ m0b1,
    const float* __restrict__ ncw1, const float* __restrict__ ncb1,
    const float* __restrict__ ncw2, const float* __restrict__ ncb2) {
  __shared__ float Wu[1024], Wv[1024];
  int tid = threadIdx.x, k = tid >> 5, g = tid & 31;
  float a = m0w1[k*32+g], b = m0w1[(k+32)*32+g], c = m0w1[(k+64)*32+g];
  Wu[tid] = a + b;  Wv[tid] = c - a;
  __syncthreads();
  float au = 0.f, av = 0.f;
  #pragma unroll
  for (int f = 0; f < 32; f++) {
    float w2 = ncw2[k*32+f];
    au = fmaf(w2, Wu[f*32+g], au);
    av = fmaf(w2, Wv[f*32+g], av);
  }
  WS_F(OFF_WCU)[tid] = au;  WS_F(OFF_WCV)[tid] = av;
  if (tid < 32) {
    float bu = 0.f, bv = 0.f;
    #pragma unroll
    for (int f = 0; f < 32; f++) {
      bu = fmaf(ncb2[f], Wu[f*32+tid], bu);
      bv = fmaf(ncb2[f], Wv[f*32+tid], bv);
    }
    WS_F(OFF_BU)[tid] = bu;
    WS_F(OFF_BV)[tid] = bv + m0b1[tid];       // fold mp0_b1 into dst-side
    WS_F(OFF_CPATH)[tid] = ncw1[64+tid]  + ncb1[tid];
    WS_F(OFF_CFREE)[tid] = ncw1[96+tid]  + ncb1[tid];
    WS_F(OFF_CCOL)[tid]  = ncw1[128+tid] + ncb1[tid];
  }
}

// hash-insert fixed edges (dedupe); compact kept edges with dst<PN; deg0 histogram
__global__ __launch_bounds__(256) void k_edges(char* __restrict__ ws,
                                               const int* __restrict__ ei) {
  int e = blockIdx.x * 256 + threadIdx.x;
  if (e >= NEDGE) return;
  int src = ei[e], dst = ei[NEDGE + e];
  unsigned long long key = (unsigned long long)src * NNODE + (unsigned long long)dst;
  unsigned long long* hash = WS_H(OFF_HASH);
  uint32_t slot = hslot(key);
  bool win = false;
  for (;;) {
    unsigned long long prev = atomicCAS(&hash[slot], EMPTYK, key);
    if (prev == EMPTYK) { win = true; break; }
    if (prev == key)    { break; }            // duplicate pair
    slot = (slot + 1) & HMASK;
  }
  if (win && dst < PN) {
    int pos = atomicAdd(WS_I(OFF_E0C), 1);
    if (pos < E0CAP) {
      WS_I(OFF_E0S)[pos] = src;
      WS_I(OFF_E0D)[pos] = dst;
      atomicAdd(&WS_I(OFF_DEG0)[dst], 1);
    }
  }
}

// ---------------- per-loop kernels ----------------

// blocks 0..PN*NPART-1: partial kNN — block (node, part) scans CPP candidates.
// block PN*NPART: BN stats + u/v for path nodes + zero S.
__global__ __launch_bounds__(256) void k_knn(char* __restrict__ ws,
    const float* __restrict__ ncw1, const float* __restrict__ gamma,
    const float* __restrict__ beta) {
  __shared__ float sd[256*11];
  __shared__ int   si[256*11];
  int tid = threadIdx.x, b = blockIdx.x;
  float* pathb = WS_F(OFF_PATH);

  if (b < PN * NPART) {
    int node = b >> 3, part = b & 7;
    const float4* cp4 = (const float4*)WS_F(OFF_CPOS);  // 2 candidates / float4
    const float4* cq4 = (const float4*)WS_F(OFF_CSQ);   // 4 candidates / float4
    float p0 = pathb[2*node], p1 = pathb[2*node+1];
    float psq = p0*p0 + p1*p1;
    int start = part * CPP;
    float bd[10]; int bi[10];
    #pragma unroll
    for (int k = 0; k < 10; k++) { bd[k] = 3.4e38f; bi[k] = 0x7FFFFFFF; }
    #pragma unroll 1
    for (int it = 0; it < KITER; it++) {
      int off = (it*256 + tid) * 4;
      if (off < CPP) {
        int j = start + off;
        float4 q  = cq4[(start >> 2) + it*256 + tid];
        float4 ca = cp4[j >> 1];
        float4 cb = cp4[(j >> 1) + 1];
        float d0 = (psq + q.x) - 2.f * fmaf(p1, ca.y, p0 * ca.x);
        float d1 = (psq + q.y) - 2.f * fmaf(p1, ca.w, p0 * ca.z);
        float d2 = (psq + q.z) - 2.f * fmaf(p1, cb.y, p0 * cb.x);
        float d3 = (psq + q.w) - 2.f * fmaf(p1, cb.w, p0 * cb.z);
        INSERT10(d0, j);
        INSERT10(d1, j+1);
        INSERT10(d2, j+2);
        INSERT10(d3, j+3);
      }
    }
    #pragma unroll
    for (int k = 0; k < 10; k++) { sd[tid*11+k] = bd[k]; si[tid*11+k] = bi[k]; }
    __syncthreads();
    for (int stride = 128; stride > 0; stride >>= 1) {
      if (tid < stride) {
        float rd[10]; int ri[10];
        int ia = 0, ib = 0;
        #pragma unroll
        for (int k = 0; k < 10; k++) {
          float da = sd[tid*11+ia],          db = sd[(tid+stride)*11+ib];
          int   xa = si[tid*11+ia],          xb = si[(tid+stride)*11+ib];
          bool takeA = lexless(da, xa, db, xb);
          if (takeA) { rd[k] = da; ri[k] = xa; ia++; }
          else       { rd[k] = db; ri[k] = xb; ib++; }
        }
        #pragma unroll
        for (int k = 0; k < 10; k++) { sd[tid*11+k] = rd[k]; si[tid*11+k] = ri[k]; }
      }
      __syncthreads();
    }
    if (tid < 10) {
      WS_F(OFF_KPD)[b*10 + tid] = sd[tid];   // row 0 of padded layout
      WS_I(OFF_KPI)[b*10 + tid] = si[tid];
    }
  } else {
    // ---- BN stats over path rows (cand part precomputed) ----
    if (tid < 64) sd[tid] = 0.f;
    __syncthreads();
    const float* cpath = WS_F(OFF_CPATH);
    for (int r = tid; r < PN; r += 256) {
      float p0 = pathb[2*r], p1 = pathb[2*r+1];
      for (int ff = 0; ff < 32; ff++) {
        int f = (tid + ff) & 31;
        float h = fmaf(p1, ncw1[32+f], fmaf(p0, ncw1[f], cpath[f]));
        atomicAdd(&sd[f], h);
        atomicAdd(&sd[32+f], h*h);
      }
    }
    __syncthreads();
    if (tid < 32) {
      float mean = (WS_F(OFF_SUMC)[tid]  + sd[tid])    * (1.f / NNODE);
      float ex2  = (WS_F(OFF_SUMC2)[tid] + sd[32+tid]) * (1.f / NNODE);
      float var  = ex2 - mean * mean;
      float rs   = 1.0f / sqrtf(var + EPSV);
      WS_F(OFF_MEAN)[tid] = mean; WS_F(OFF_RSTD)[tid] = rs;
      sd[64+tid] = mean; sd[96+tid] = rs;
    }
    __syncthreads();
    // ---- u/v for all 512 path nodes ----
    const float* wcu = WS_F(OFF_WCU); const float* wcv = WS_F(OFF_WCV);
    const float* bu  = WS_F(OFF_BU);  const float* bv  = WS_F(OFF_BV);
    for (int i = tid; i < PN; i += 256) {
      float p0 = pathb[2*i], p1 = pathb[2*i+1];
      float xn[32];
      #pragma unroll
      for (int f = 0; f < 32; f++) {
        float h = fmaf(p1, ncw1[32+f], fmaf(p0, ncw1[f], cpath[f]));
        float t = (h - sd[64+f]) * sd[96+f];
        t = fmaf(t, gamma[f], beta[f]);
        xn[f] = t > 0.f ? t : 0.f;
      }
      for (int f = 0; f < 32; f++) {
        float au = bu[f], av = bv[f];
        #pragma unroll
        for (int k = 0; k < 32; k++) {
          au = fmaf(xn[k], wcu[k*32+f], au);
          av = fmaf(xn[k], wcv[k*32+f], av);
        }
        WS_F(OFF_UPATH)[i*32+f] = au;
        WS_F(OFF_VDST)[i*32+f]  = av;
      }
    }
    for (int i = tid; i < PN*32; i += 256) WS_F(OFF_SBUF)[i] = 0.f;
  }
}

// merge 8 partial top-10 lists per node by ranking; probe hash for keep flags
__global__ __launch_bounds__(64) void k_sel(char* __restrict__ ws) {
  __shared__ float ed[80];
  __shared__ int   ex[80];
  int node = blockIdx.x, tid = threadIdx.x;
  const float* kpd = &WS_F(OFF_KPD)[node*80];
  const int*   kpi = &WS_I(OFF_KPI)[node*80];
  ed[tid] = kpd[tid];  ex[tid] = kpi[tid];
  if (tid < 16) { ed[64+tid] = kpd[64+tid]; ex[64+tid] = kpi[64+tid]; }
  __syncthreads();
  unsigned long long* hash = WS_H(OFF_HASH);
  #pragma unroll
  for (int pass = 0; pass < 2; pass++) {
    int e = tid + pass*64;
    if (pass == 1 && tid >= 16) break;
    float de = ed[e]; int xe = ex[e];
    int r = 0;
    for (int f = 0; f < 80; f++) r += lexless(ed[f], ex[f], de, xe) ? 1 : 0;
    if (r < 10) {
      int srcg = xe + PN;
      unsigned long long key = (unsigned long long)srcg * NNODE + (unsigned long long)node;
      uint32_t slot = hslot(key);
      int keep = 1;
      for (;;) {
        unsigned long long v = hash[slot];
        if (v == EMPTYK) break;
        if (v == key) { keep = 0; break; }    // duplicate of a fixed edge
        slot = (slot + 1) & HMASK;
      }
      WS_I(OFF_KSRC)[node*KK+r]  = srcg;
      WS_I(OFF_KKEEP)[node*KK+r] = keep;
    }
  }
}

// per-edge: r = relu(u[src]+v[dst]) accumulated into S[dst]
__global__ __launch_bounds__(256) void k_loopB(char* __restrict__ ws,
    const float* __restrict__ ncw1, const float* __restrict__ gamma,
    const float* __restrict__ beta) {
  int t = blockIdx.x * 256 + threadIdx.x;
  int src, dst;
  if (t < PN*KK) {
    dst = t / KK;
    src = WS_I(OFF_KSRC)[t];
    if (!WS_I(OFF_KKEEP)[t]) return;
  } else {
    int e = t - PN*KK;
    if (e >= *WS_I(OFF_E0C)) return;
    src = WS_I(OFF_E0S)[e];
    dst = WS_I(OFF_E0D)[e];
  }
  float u[32];
  if (src < PN) {
    const float4* up4 = (const float4*)&WS_F(OFF_UPATH)[src*32];
    #pragma unroll
    for (int q = 0; q < 8; q++) {
      float4 w = up4[q];
      u[4*q] = w.x; u[4*q+1] = w.y; u[4*q+2] = w.z; u[4*q+3] = w.w;
    }
  } else {
    int j = src - PN;
    float c0 = WS_F(OFF_CPOS)[2*j], c1 = WS_F(OFF_CPOS)[2*j+1];
    const float* cls = (j < NFREE) ? WS_F(OFF_CFREE) : WS_F(OFF_CCOL);
    const float* mean = WS_F(OFF_MEAN); const float* rstd = WS_F(OFF_RSTD);
    float xn[32];
    #pragma unroll
    for (int f = 0; f < 32; f++) {
      float h = fmaf(c1, ncw1[32+f], fmaf(c0, ncw1[f], cls[f]));
      float tt = (h - mean[f]) * rstd[f];
      tt = fmaf(tt, gamma[f], beta[f]);
      xn[f] = tt > 0.f ? tt : 0.f;
    }
    const float* wcu = WS_F(OFF_WCU); const float* bu = WS_F(OFF_BU);
    for (int f = 0; f < 32; f++) {
      float au = bu[f];
      #pragma unroll
      for (int k = 0; k < 32; k++) au = fmaf(xn[k], wcu[k*32+f], au);
      u[f] = au;
    }
  }
  const float* vd = &WS_F(OFF_VDST)[dst*32];
  float* sb = &WS_F(OFF_SBUF)[dst*32];
  #pragma unroll
  for (int f = 0; f < 32; f++) {
    float r = u[f] + vd[f];
    if (r > 0.f) atomicAdd(&sb[f], r);        // relu; skip zero adds
  }
}

// epilogue per path node: out -> mp1 -> h = x + g -> smooth -> path update + d_out
__global__ __launch_bounds__(256) void k_loopC(char* __restrict__ ws,
    const float* __restrict__ ncw1, const float* __restrict__ gamma,
    const float* __restrict__ beta, const float* __restrict__ ncw2,
    const float* __restrict__ ncb2, const float* __restrict__ m0w2,
    const float* __restrict__ m0b2, const float* __restrict__ m1w1,
    const float* __restrict__ m1b1, const float* __restrict__ m1w2,
    const float* __restrict__ m1b2, const float* __restrict__ snw,
    const float* __restrict__ snb, float* __restrict__ outp) {
  int i = blockIdx.x * 256 + threadIdx.x;
  if (i >= PN) return;
  float s[32];
  #pragma unroll
  for (int f = 0; f < 32; f++) s[f] = WS_F(OFF_SBUF)[i*32+f];
  int deg = WS_I(OFF_DEG0)[i];
  #pragma unroll
  for (int k = 0; k < KK; k++) deg += WS_I(OFF_KKEEP)[i*KK+k];
  float fdeg = (float)deg;

  float o[32];
  for (int f = 0; f < 32; f++) {
    float acc = 0.f;
    #pragma unroll
    for (int k = 0; k < 32; k++) acc = fmaf(s[k], m0w2[k*32+f], acc);
    o[f] = fmaf(fdeg, m0b2[f], acc);
  }
  float t[32];
  for (int f = 0; f < 32; f++) {
    float acc = m1b1[f];
    #pragma unroll
    for (int k = 0; k < 32; k++) acc = fmaf(o[k], m1w1[k*32+f], acc);
    t[f] = acc > 0.f ? acc : 0.f;
  }
  float g[32];
  for (int f = 0; f < 32; f++) {
    float acc = m1b2[f];
    #pragma unroll
    for (int k = 0; k < 32; k++) acc = fmaf(t[k], m1w2[k*32+f], acc);
    g[f] = acc;
  }
  // x_i for this path node
  float p0 = WS_F(OFF_PATH)[2*i], p1 = WS_F(OFF_PATH)[2*i+1];
  const float* cpath = WS_F(OFF_CPATH);
  const float* mean = WS_F(OFF_MEAN); const float* rstd = WS_F(OFF_RSTD);
  float xn[32];
  #pragma unroll
  for (int f = 0; f < 32; f++) {
    float h = fmaf(p1, ncw1[32+f], fmaf(p0, ncw1[f], cpath[f]));
    float tt = (h - mean[f]) * rstd[f];
    tt = fmaf(tt, gamma[f], beta[f]);
    xn[f] = tt > 0.f ? tt : 0.f;
  }
  float sm0 = snb[0], sm1 = snb[1];
  for (int f = 0; f < 32; f++) {
    float acc = ncb2[f];
    #pragma unroll
    for (int k = 0; k < 32; k++) acc = fmaf(xn[k], ncw2[k*32+f], acc);
    float h = acc + g[f];
    sm0 = fmaf(h, snw[2*f],   sm0);
    sm1 = fmaf(h, snw[2*f+1], sm1);
  }
  float np0, np1;
  if (i == 0 || i == PN-1) { np0 = p0; np1 = p1; }  // endpoints fixed
  else                     { np0 = sm0; np1 = sm1; }
  WS_F(OFF_PATH)[2*i]   = np0;
  WS_F(OFF_PATH)[2*i+1] = np1;
  outp[2*i]   = np0;
  outp[2*i+1] = np1;
}

// ---------------- host launch ----------------

extern "C" void kernel_launch(void* const* d_in, const int* in_sizes, int n_in,
                              void* d_out, int out_size, void* d_ws, size_t ws_size,
                              hipStream_t stream) {
  const float* path  = (const float*)d_in[0];
  const float* freep = (const float*)d_in[1];
  const float* collp = (const float*)d_in[2];
  const int*   ei    = (const int*)d_in[4];
  const float* ncw1  = (const float*)d_in[6];
  const float* ncb1  = (const float*)d_in[7];
  const float* gamma = (const float*)d_in[8];
  const float* beta  = (const float*)d_in[9];
  const float* ncw2  = (const float*)d_in[10];
  const float* ncb2  = (const float*)d_in[11];
  const float* m0w1  = (const float*)d_in[12];
  const float* m0b1  = (const float*)d_in[13];
  const float* m0w2  = (const float*)d_in[14];
  const float* m0b2  = (const float*)d_in[15];
  const float* m1w1  = (const float*)d_in[16];
  const float* m1b1  = (const float*)d_in[17];
  const float* m1w2  = (const float*)d_in[18];
  const float* m1b2  = (const float*)d_in[19];
  const float* snw   = (const float*)d_in[20];
  const float* snb   = (const float*)d_in[21];
  char* ws = (char*)d_ws;

  k_init <<<HSIZE/256, 256, 0, stream>>>(ws, path);
  k_cand <<<(NCND+255)/256, 256, 0, stream>>>(ws, freep, collp, ncw1, ncb1);
  k_wprep<<<1, 1024, 0, stream>>>(ws, m0w1, m0b1, ncw1, ncb1, ncw2, ncb2);
  k_edges<<<(NEDGE+255)/256, 256, 0, stream>>>(ws, ei);

  for (int l = 0; l < NLOOP; l++) {
    k_knn <<<PN*NPART + 1, 256, 0, stream>>>(ws, ncw1, gamma, beta);
    k_sel <<<PN, 64, 0, stream>>>(ws);
    k_loopB<<<(PN*KK + E0CAP + 255)/256, 256, 0, stream>>>(ws, ncw1, gamma, beta);
    k_loopC<<<2, 256, 0, stream>>>(ws, ncw1, gamma, beta, ncw2, ncb2,
                                   m0w2, m0b2, m1w1, m1b1, m1w2, m1b2,
                                   snw, snb, (float*)d_out);
  }
}

// Round 3
// 1739.466 us; speedup vs baseline: 2.1247x; 2.1247x over previous
//
#include <hip/hip_runtime.h>
#include <stdint.h>

// Problem constants (fixed by setup_inputs)
#define PN     512
#define NFREE  50000
#define NCND   100000
#define NNODE  100512
#define NEDGE  300000
#define KK     10
#define NLOOP  5
#define EPSV   1e-5f

#define GRID   128
#define NCELL  (GRID*GRID)

#define HSIZE  (1u<<19)
#define HMASK  (HSIZE-1)
#define E0CAP  4096
#define EMPTYK 0xFFFFFFFFFFFFFFFFull

// workspace layout (bytes, every block 64-aligned) — total ~7.4 MB
#define OFF_HASH   ((size_t)0)
#define OFF_CPOS   (OFF_HASH   + (size_t)HSIZE*8)        // 800000
#define OFF_CSQ    (OFF_CPOS   + 800000)                 // 400000
#define OFF_SCND   (OFF_CSQ    + 400000)                 // 1600000 (float4/cand, cell-sorted)
#define OFF_CSTART (OFF_SCND   + 1600000)                // 65600 (NCELL+1 ints)
#define OFF_COFS   (OFF_CSTART + 65600)                  // 65600
#define OFF_MNMX   (OFF_COFS   + 65600)                  // 64 (4 encoded uints)
#define OFF_SUMC   (OFF_MNMX   + 64)
#define OFF_SUMC2  (OFF_SUMC   + 128)
#define OFF_MEAN   (OFF_SUMC2  + 128)
#define OFF_RSTD   (OFF_MEAN   + 128)
#define OFF_WCU    (OFF_RSTD   + 128)
#define OFF_WCV    (OFF_WCU    + 4096)
#define OFF_BU     (OFF_WCV    + 4096)
#define OFF_BV     (OFF_BU     + 128)
#define OFF_CPATH  (OFF_BV     + 128)
#define OFF_CFREE  (OFF_CPATH  + 128)
#define OFF_CCOL   (OFF_CFREE  + 128)
#define OFF_PATH   (OFF_CCOL   + 128)
#define OFF_UPATH  (OFF_PATH   + 4096)                   // 65536
#define OFF_VDST   (OFF_UPATH  + 65536)
#define OFF_SBUF   (OFF_VDST   + 65536)
#define OFF_E0S    (OFF_SBUF   + 65536)
#define OFF_E0D    (OFF_E0S    + (size_t)E0CAP*4)
#define OFF_DEG0   (OFF_E0D    + (size_t)E0CAP*4)
#define OFF_E0C    (OFF_DEG0   + 2048)
#define OFF_KSRC   (OFF_E0C    + 64)
#define OFF_KKEEP  (OFF_KSRC   + (size_t)PN*KK*4)

#define WS_F(o)  ((float*)(ws + (o)))
#define WS_I(o)  ((int*)(ws + (o)))
#define WS_U(o)  ((unsigned*)(ws + (o)))
#define WS_H(o)  ((unsigned long long*)(ws + (o)))

__device__ __forceinline__ bool lexless(float da, int ia, float db, int ib) {
  return (da < db) || (da == db && ia < ib);
}

__device__ __forceinline__ uint32_t hslot(unsigned long long key) {
  return (uint32_t)((key * 0x9E3779B97F4A7C15ull) >> 40) & HMASK;
}

// monotone float<->uint order encoding (for atomicMin/Max on floats)
__device__ __forceinline__ unsigned encf(float f) {
  unsigned u = __float_as_uint(f);
  return (u & 0x80000000u) ? ~u : (u | 0x80000000u);
}
__device__ __forceinline__ float decf(unsigned u) {
  return (u & 0x80000000u) ? __uint_as_float(u & 0x7FFFFFFFu) : __uint_as_float(~u);
}

#define INSERT10(d2v, jv)                                                  \
  if (lexless((d2v), (jv), bd[9], bi[9])) {                                \
    bool placed = false;                                                   \
    _Pragma("unroll")                                                      \
    for (int k = 9; k > 0; k--) {                                          \
      bool shift = !placed && lexless((d2v), (jv), bd[k-1], bi[k-1]);      \
      bool here  = !placed && !shift;                                      \
      if (here)       { bd[k] = (d2v); bi[k] = (jv); placed = true; }      \
      else if (shift) { bd[k] = bd[k-1]; bi[k] = bi[k-1]; }                \
    }                                                                      \
    if (!placed) { bd[0] = (d2v); bi[0] = (jv); }                          \
  }

// ---------------- setup kernels (once per launch) ----------------

__global__ __launch_bounds__(256) void k_init(char* __restrict__ ws,
                                              const float* __restrict__ path_in) {
  unsigned i = blockIdx.x * 256u + threadIdx.x;       // grid = HSIZE/256
  WS_H(OFF_HASH)[i] = EMPTYK;
  if (i < NCELL+1) WS_I(OFF_CSTART)[i] = 0;
  if (i < 1024) WS_F(OFF_PATH)[i] = path_in[i];
  if (i < 512)  WS_I(OFF_DEG0)[i] = 0;
  if (i < 32) { WS_F(OFF_SUMC)[i] = 0.f; WS_F(OFF_SUMC2)[i] = 0.f; }
  if (i < 4)  WS_U(OFF_MNMX)[i] = (i & 1) ? 0u : 0xFFFFFFFFu;  // min=UINT_MAX, max=0
  if (i == 0)   *WS_I(OFF_E0C) = 0;
}

// candidate positions, norms, BN partial sums, bbox min/max
__global__ __launch_bounds__(256) void k_cand(char* __restrict__ ws,
    const float* __restrict__ freep, const float* __restrict__ collp,
    const float* __restrict__ ncw1, const float* __restrict__ ncb1) {
  __shared__ float ls[64];
  __shared__ unsigned mm[4];
  int tid = threadIdx.x;
  if (tid < 64) ls[tid] = 0.f;
  if (tid < 4)  mm[tid] = (tid & 1) ? 0u : 0xFFFFFFFFu;
  __syncthreads();
  int j = blockIdx.x * 256 + tid;
  float c0 = 0.f, c1 = 0.f;
  bool valid = (j < NCND);
  if (valid) {
    if (j < NFREE) { c0 = freep[2*j];          c1 = freep[2*j+1]; }
    else           { c0 = collp[2*(j-NFREE)];  c1 = collp[2*(j-NFREE)+1]; }
    WS_F(OFF_CPOS)[2*j] = c0; WS_F(OFF_CPOS)[2*j+1] = c1;
    WS_F(OFF_CSQ)[j] = c0*c0 + c1*c1;
    atomicMin(&mm[0], encf(c0)); atomicMax(&mm[1], encf(c0));
    atomicMin(&mm[2], encf(c1)); atomicMax(&mm[3], encf(c1));
  }
  for (int ff = 0; ff < 32; ff++) {
    int f = (tid + ff) & 31;
    if (valid) {
      float cls = (j < NFREE) ? (ncw1[96+f] + ncb1[f]) : (ncw1[128+f] + ncb1[f]);
      float h = fmaf(c1, ncw1[32+f], fmaf(c0, ncw1[f], cls));
      atomicAdd(&ls[f], h);
      atomicAdd(&ls[32+f], h*h);
    }
  }
  __syncthreads();
  if (tid < 32) {
    atomicAdd(&WS_F(OFF_SUMC)[tid],  ls[tid]);
    atomicAdd(&WS_F(OFF_SUMC2)[tid], ls[32+tid]);
  }
  if (tid < 4) {
    if (tid & 1) atomicMax(&WS_U(OFF_MNMX)[tid], mm[tid]);
    else         atomicMin(&WS_U(OFF_MNMX)[tid], mm[tid]);
  }
}

// combined weights: Wcu = ncW2·(W1a+W1b), Wcv = ncW2·(W1c−W1a), biases, class consts
__global__ __launch_bounds__(1024) void k_wprep(char* __restrict__ ws,
    const float* __restrict__ m0w1, const float* __restrict__ m0b1,
    const float* __restrict__ ncw1, const float* __restrict__ ncb1,
    const float* __restrict__ ncw2, const float* __restrict__ ncb2) {
  __shared__ float Wu[1024], Wv[1024];
  int tid = threadIdx.x, k = tid >> 5, g = tid & 31;
  float a = m0w1[k*32+g], b = m0w1[(k+32)*32+g], c = m0w1[(k+64)*32+g];
  Wu[tid] = a + b;  Wv[tid] = c - a;
  __syncthreads();
  float au = 0.f, av = 0.f;
  #pragma unroll
  for (int f = 0; f < 32; f++) {
    float w2 = ncw2[k*32+f];
    au = fmaf(w2, Wu[f*32+g], au);
    av = fmaf(w2, Wv[f*32+g], av);
  }
  WS_F(OFF_WCU)[tid] = au;  WS_F(OFF_WCV)[tid] = av;
  if (tid < 32) {
    float bu = 0.f, bv = 0.f;
    #pragma unroll
    for (int f = 0; f < 32; f++) {
      bu = fmaf(ncb2[f], Wu[f*32+tid], bu);
      bv = fmaf(ncb2[f], Wv[f*32+tid], bv);
    }
    WS_F(OFF_BU)[tid] = bu;
    WS_F(OFF_BV)[tid] = bv + m0b1[tid];
    WS_F(OFF_CPATH)[tid] = ncw1[64+tid]  + ncb1[tid];
    WS_F(OFF_CFREE)[tid] = ncw1[96+tid]  + ncb1[tid];
    WS_F(OFF_CCOL)[tid]  = ncw1[128+tid] + ncb1[tid];
  }
}

// hash-insert fixed edges (dedupe); compact kept edges with dst<PN; deg0 histogram
__global__ __launch_bounds__(256) void k_edges(char* __restrict__ ws,
                                               const int* __restrict__ ei) {
  int e = blockIdx.x * 256 + threadIdx.x;
  if (e >= NEDGE) return;
  int src = ei[e], dst = ei[NEDGE + e];
  unsigned long long key = (unsigned long long)src * NNODE + (unsigned long long)dst;
  unsigned long long* hash = WS_H(OFF_HASH);
  uint32_t slot = hslot(key);
  bool win = false;
  for (;;) {
    unsigned long long prev = atomicCAS(&hash[slot], EMPTYK, key);
    if (prev == EMPTYK) { win = true; break; }
    if (prev == key)    { break; }
    slot = (slot + 1) & HMASK;
  }
  if (win && dst < PN) {
    int pos = atomicAdd(WS_I(OFF_E0C), 1);
    if (pos < E0CAP) {
      WS_I(OFF_E0S)[pos] = src;
      WS_I(OFF_E0D)[pos] = dst;
      atomicAdd(&WS_I(OFF_DEG0)[dst], 1);
    }
  }
}

// grid histogram over candidate cells
__global__ __launch_bounds__(256) void k_hist(char* __restrict__ ws) {
  int j = blockIdx.x * 256 + threadIdx.x;
  if (j >= NCND) return;
  const unsigned* mnmx = WS_U(OFF_MNMX);
  float xmin = decf(mnmx[0]), xmax = decf(mnmx[1]);
  float ymin = decf(mnmx[2]), ymax = decf(mnmx[3]);
  float ivx = (float)GRID / ((xmax - xmin) * 1.000001f + 1e-30f);
  float ivy = (float)GRID / ((ymax - ymin) * 1.000001f + 1e-30f);
  float c0 = WS_F(OFF_CPOS)[2*j], c1 = WS_F(OFF_CPOS)[2*j+1];
  int cx = min(GRID-1, max(0, (int)((c0 - xmin) * ivx)));
  int cy = min(GRID-1, max(0, (int)((c1 - ymin) * ivy)));
  atomicAdd(&WS_I(OFF_CSTART)[cy*GRID + cx], 1);
}

// exclusive scan of cell counts (single block)
__global__ __launch_bounds__(256) void k_scan(char* __restrict__ ws) {
  __shared__ int part[256];
  int tid = threadIdx.x;
  int* cnt = WS_I(OFF_CSTART);
  int base = tid * (NCELL/256);     // 64 cells per thread
  int sum = 0;
  for (int k = 0; k < NCELL/256; k++) sum += cnt[base+k];
  part[tid] = sum;
  __syncthreads();
  for (int off = 1; off < 256; off <<= 1) {
    int t = (tid >= off) ? part[tid - off] : 0;
    __syncthreads();
    part[tid] += t;
    __syncthreads();
  }
  int run = part[tid] - sum;        // exclusive base
  for (int k = 0; k < NCELL/256; k++) {
    int c = cnt[base+k];
    cnt[base+k] = run;
    WS_I(OFF_COFS)[base+k] = run;
    run += c;
  }
  if (tid == 255) cnt[NCELL] = run;
}

// scatter candidates into cell-sorted float4 array (x, y, |c|^2, idx)
__global__ __launch_bounds__(256) void k_scatter(char* __restrict__ ws) {
  int j = blockIdx.x * 256 + threadIdx.x;
  if (j >= NCND) return;
  const unsigned* mnmx = WS_U(OFF_MNMX);
  float xmin = decf(mnmx[0]), xmax = decf(mnmx[1]);
  float ymin = decf(mnmx[2]), ymax = decf(mnmx[3]);
  float ivx = (float)GRID / ((xmax - xmin) * 1.000001f + 1e-30f);
  float ivy = (float)GRID / ((ymax - ymin) * 1.000001f + 1e-30f);
  float c0 = WS_F(OFF_CPOS)[2*j], c1 = WS_F(OFF_CPOS)[2*j+1];
  int cx = min(GRID-1, max(0, (int)((c0 - xmin) * ivx)));
  int cy = min(GRID-1, max(0, (int)((c1 - ymin) * ivy)));
  int pos = atomicAdd(&WS_I(OFF_COFS)[cy*GRID + cx], 1);
  ((float4*)(ws + OFF_SCND))[pos] =
      make_float4(c0, c1, WS_F(OFF_CSQ)[j], __int_as_float(j));
}

// ---------------- per-loop kernels ----------------

#define SCAN_CELL(CX, CY) do {                                             \
    int _c = (CY) * GRID + (CX);                                           \
    int _s = cst[_c], _e = cst[_c+1];                                      \
    for (int _t = _s + lane; _t < _e; _t += 64) {                          \
      float4 _q = scnd[_t];                                                \
      float _d2 = (psq + _q.z) - 2.f * fmaf(p1, _q.y, p0 * _q.x);          \
      int _j = __float_as_int(_q.w);                                       \
      INSERT10(_d2, _j);                                                   \
    }                                                                      \
  } while (0)

// non-destructive wave top-10 pop-merge: refreshes cur10d, lane r stores r-th idx
#define MERGEPOP() do {                                                    \
    float cd[10]; int ci[10];                                              \
    _Pragma("unroll")                                                      \
    for (int k = 0; k < 10; k++) { cd[k] = bd[k]; ci[k] = bi[k]; }         \
    _Pragma("unroll")                                                      \
    for (int r = 0; r < 10; r++) {                                         \
      float md = cd[0]; int mi = ci[0];                                    \
      _Pragma("unroll")                                                    \
      for (int off = 32; off >= 1; off >>= 1) {                            \
        float od = __shfl_xor(md, off);                                    \
        int   oi = __shfl_xor(mi, off);                                    \
        if (lexless(od, oi, md, mi)) { md = od; mi = oi; }                 \
      }                                                                    \
      bool win = (cd[0] == md) && (ci[0] == mi);                           \
      if (win) {                                                           \
        _Pragma("unroll")                                                  \
        for (int k = 0; k < 9; k++) { cd[k] = cd[k+1]; ci[k] = ci[k+1]; }  \
        cd[9] = 3.4e38f; ci[9] = 0x7FFFFFFF;                               \
      }                                                                    \
      if (lane == r) selIdx = mi;                                          \
      cur10d = md;                                                         \
    }                                                                      \
  } while (0)

// blocks 0..127: one wave per path node — grid-kNN + dedup probe + KSRC/KKEEP.
// block 128: BN stats + u/v for path nodes + zero SBUF.
__global__ __launch_bounds__(256) void k_knng(char* __restrict__ ws,
    const float* __restrict__ ncw1, const float* __restrict__ gamma,
    const float* __restrict__ beta) {
  __shared__ float ps[128];
  int tid = threadIdx.x, b = blockIdx.x;
  float* pathb = WS_F(OFF_PATH);

  if (b < PN/4) {
    int lane = tid & 63, wave = tid >> 6;
    int node = (b << 2) + wave;
    const float4* scnd = (const float4*)(ws + OFF_SCND);
    const int* cst = WS_I(OFF_CSTART);
    const unsigned* mnmx = WS_U(OFF_MNMX);
    float xmin = decf(mnmx[0]), xmax = decf(mnmx[1]);
    float ymin = decf(mnmx[2]), ymax = decf(mnmx[3]);
    float spx = (xmax - xmin) * 1.000001f + 1e-30f;
    float spy = (ymax - ymin) * 1.000001f + 1e-30f;
    float ivx = (float)GRID / spx, ivy = (float)GRID / spy;
    float cwmin = fminf(spx, spy) * (1.0f / GRID);
    float p0 = pathb[2*node], p1 = pathb[2*node+1];
    float psq = p0*p0 + p1*p1;
    int cx = min(GRID-1, max(0, (int)((p0 - xmin) * ivx)));
    int cy = min(GRID-1, max(0, (int)((p1 - ymin) * ivy)));

    float bd[10]; int bi[10];
    #pragma unroll
    for (int k = 0; k < 10; k++) { bd[k] = 3.4e38f; bi[k] = 0x7FFFFFFF; }
    float cur10d = 3.4e38f;
    int selIdx = 0x7FFFFFFF;

    for (int rho = 0; rho < GRID; rho++) {
      if (rho > 0) {
        float dmin = (float)(rho - 1) * cwmin;
        if (dmin * dmin > cur10d) break;      // exact conservative prune
      }
      if (rho == 0) {
        SCAN_CELL(cx, cy);
      } else {
        int xa = cx-rho < 0 ? 0 : cx-rho;
        int xb = cx+rho > GRID-1 ? GRID-1 : cx+rho;
        if (cy-rho >= 0)   for (int x = xa; x <= xb; x++) SCAN_CELL(x, cy-rho);
        if (cy+rho < GRID) for (int x = xa; x <= xb; x++) SCAN_CELL(x, cy+rho);
        int ya = cy-rho+1 < 0 ? 0 : cy-rho+1;
        int yb = cy+rho-1 > GRID-1 ? GRID-1 : cy+rho-1;
        if (cx-rho >= 0)   for (int y = ya; y <= yb; y++) SCAN_CELL(cx-rho, y);
        if (cx+rho < GRID) for (int y = ya; y <= yb; y++) SCAN_CELL(cx+rho, y);
      }
      MERGEPOP();
    }
    // lanes 0..9 hold the rank-r neighbor; dedup-probe vs fixed edges, write out
    if (lane < KK) {
      int srcg = selIdx + PN;
      unsigned long long key = (unsigned long long)srcg * NNODE + (unsigned long long)node;
      unsigned long long* hash = WS_H(OFF_HASH);
      uint32_t slot = hslot(key);
      int keep = 1;
      for (;;) {
        unsigned long long v = hash[slot];
        if (v == EMPTYK) break;
        if (v == key) { keep = 0; break; }
        slot = (slot + 1) & HMASK;
      }
      WS_I(OFF_KSRC)[node*KK+lane]  = srcg;
      WS_I(OFF_KKEEP)[node*KK+lane] = keep;
    }
  } else {
    // ---- BN stats over path rows (cand part precomputed) ----
    if (tid < 64) ps[tid] = 0.f;
    __syncthreads();
    const float* cpath = WS_F(OFF_CPATH);
    for (int r = tid; r < PN; r += 256) {
      float p0 = pathb[2*r], p1 = pathb[2*r+1];
      for (int ff = 0; ff < 32; ff++) {
        int f = (tid + ff) & 31;
        float h = fmaf(p1, ncw1[32+f], fmaf(p0, ncw1[f], cpath[f]));
        atomicAdd(&ps[f], h);
        atomicAdd(&ps[32+f], h*h);
      }
    }
    __syncthreads();
    if (tid < 32) {
      float mean = (WS_F(OFF_SUMC)[tid]  + ps[tid])    * (1.f / NNODE);
      float ex2  = (WS_F(OFF_SUMC2)[tid] + ps[32+tid]) * (1.f / NNODE);
      float var  = ex2 - mean * mean;
      float rs   = 1.0f / sqrtf(var + EPSV);
      WS_F(OFF_MEAN)[tid] = mean; WS_F(OFF_RSTD)[tid] = rs;
      ps[64+tid] = mean; ps[96+tid] = rs;
    }
    __syncthreads();
    // ---- u/v for all 512 path nodes ----
    const float* wcu = WS_F(OFF_WCU); const float* wcv = WS_F(OFF_WCV);
    const float* bu  = WS_F(OFF_BU);  const float* bv  = WS_F(OFF_BV);
    for (int i = tid; i < PN; i += 256) {
      float p0 = pathb[2*i], p1 = pathb[2*i+1];
      float xn[32];
      #pragma unroll
      for (int f = 0; f < 32; f++) {
        float h = fmaf(p1, ncw1[32+f], fmaf(p0, ncw1[f], cpath[f]));
        float t = (h - ps[64+f]) * ps[96+f];
        t = fmaf(t, gamma[f], beta[f]);
        xn[f] = t > 0.f ? t : 0.f;
      }
      for (int f = 0; f < 32; f++) {
        float au = bu[f], av = bv[f];
        #pragma unroll
        for (int k = 0; k < 32; k++) {
          au = fmaf(xn[k], wcu[k*32+f], au);
          av = fmaf(xn[k], wcv[k*32+f], av);
        }
        WS_F(OFF_UPATH)[i*32+f] = au;
        WS_F(OFF_VDST)[i*32+f]  = av;
      }
    }
    for (int i = tid; i < PN*32; i += 256) WS_F(OFF_SBUF)[i] = 0.f;
  }
}

// per-edge: r = relu(u[src]+v[dst]) accumulated into S[dst]
__global__ __launch_bounds__(256) void k_loopB(char* __restrict__ ws,
    const float* __restrict__ ncw1, const float* __restrict__ gamma,
    const float* __restrict__ beta) {
  int t = blockIdx.x * 256 + threadIdx.x;
  int src, dst;
  if (t < PN*KK) {
    dst = t / KK;
    src = WS_I(OFF_KSRC)[t];
    if (!WS_I(OFF_KKEEP)[t]) return;
  } else {
    int e = t - PN*KK;
    if (e >= *WS_I(OFF_E0C)) return;
    src = WS_I(OFF_E0S)[e];
    dst = WS_I(OFF_E0D)[e];
  }
  float u[32];
  if (src < PN) {
    const float4* up4 = (const float4*)&WS_F(OFF_UPATH)[src*32];
    #pragma unroll
    for (int q = 0; q < 8; q++) {
      float4 w = up4[q];
      u[4*q] = w.x; u[4*q+1] = w.y; u[4*q+2] = w.z; u[4*q+3] = w.w;
    }
  } else {
    int j = src - PN;
    float c0 = WS_F(OFF_CPOS)[2*j], c1 = WS_F(OFF_CPOS)[2*j+1];
    const float* cls = (j < NFREE) ? WS_F(OFF_CFREE) : WS_F(OFF_CCOL);
    const float* mean = WS_F(OFF_MEAN); const float* rstd = WS_F(OFF_RSTD);
    float xn[32];
    #pragma unroll
    for (int f = 0; f < 32; f++) {
      float h = fmaf(c1, ncw1[32+f], fmaf(c0, ncw1[f], cls[f]));
      float tt = (h - mean[f]) * rstd[f];
      tt = fmaf(tt, gamma[f], beta[f]);
      xn[f] = tt > 0.f ? tt : 0.f;
    }
    const float* wcu = WS_F(OFF_WCU); const float* bu = WS_F(OFF_BU);
    for (int f = 0; f < 32; f++) {
      float au = bu[f];
      #pragma unroll
      for (int k = 0; k < 32; k++) au = fmaf(xn[k], wcu[k*32+f], au);
      u[f] = au;
    }
  }
  const float* vd = &WS_F(OFF_VDST)[dst*32];
  float* sb = &WS_F(OFF_SBUF)[dst*32];
  #pragma unroll
  for (int f = 0; f < 32; f++) {
    float r = u[f] + vd[f];
    if (r > 0.f) atomicAdd(&sb[f], r);
  }
}

// epilogue per path node: out -> mp1 -> h = x + g -> smooth -> path update + d_out
__global__ __launch_bounds__(256) void k_loopC(char* __restrict__ ws,
    const float* __restrict__ ncw1, const float* __restrict__ gamma,
    const float* __restrict__ beta, const float* __restrict__ ncw2,
    const float* __restrict__ ncb2, const float* __restrict__ m0w2,
    const float* __restrict__ m0b2, const float* __restrict__ m1w1,
    const float* __restrict__ m1b1, const float* __restrict__ m1w2,
    const float* __restrict__ m1b2, const float* __restrict__ snw,
    const float* __restrict__ snb, float* __restrict__ outp) {
  int i = blockIdx.x * 256 + threadIdx.x;
  if (i >= PN) return;
  float s[32];
  #pragma unroll
  for (int f = 0; f < 32; f++) s[f] = WS_F(OFF_SBUF)[i*32+f];
  int deg = WS_I(OFF_DEG0)[i];
  #pragma unroll
  for (int k = 0; k < KK; k++) deg += WS_I(OFF_KKEEP)[i*KK+k];
  float fdeg = (float)deg;

  float o[32];
  for (int f = 0; f < 32; f++) {
    float acc = 0.f;
    #pragma unroll
    for (int k = 0; k < 32; k++) acc = fmaf(s[k], m0w2[k*32+f], acc);
    o[f] = fmaf(fdeg, m0b2[f], acc);
  }
  float t[32];
  for (int f = 0; f < 32; f++) {
    float acc = m1b1[f];
    #pragma unroll
    for (int k = 0; k < 32; k++) acc = fmaf(o[k], m1w1[k*32+f], acc);
    t[f] = acc > 0.f ? acc : 0.f;
  }
  float g[32];
  for (int f = 0; f < 32; f++) {
    float acc = m1b2[f];
    #pragma unroll
    for (int k = 0; k < 32; k++) acc = fmaf(t[k], m1w2[k*32+f], acc);
    g[f] = acc;
  }
  float p0 = WS_F(OFF_PATH)[2*i], p1 = WS_F(OFF_PATH)[2*i+1];
  const float* cpath = WS_F(OFF_CPATH);
  const float* mean = WS_F(OFF_MEAN); const float* rstd = WS_F(OFF_RSTD);
  float xn[32];
  #pragma unroll
  for (int f = 0; f < 32; f++) {
    float h = fmaf(p1, ncw1[32+f], fmaf(p0, ncw1[f], cpath[f]));
    float tt = (h - mean[f]) * rstd[f];
    tt = fmaf(tt, gamma[f], beta[f]);
    xn[f] = tt > 0.f ? tt : 0.f;
  }
  float sm0 = snb[0], sm1 = snb[1];
  for (int f = 0; f < 32; f++) {
    float acc = ncb2[f];
    #pragma unroll
    for (int k = 0; k < 32; k++) acc = fmaf(xn[k], ncw2[k*32+f], acc);
    float h = acc + g[f];
    sm0 = fmaf(h, snw[2*f],   sm0);
    sm1 = fmaf(h, snw[2*f+1], sm1);
  }
  float np0, np1;
  if (i == 0 || i == PN-1) { np0 = p0; np1 = p1; }
  else                     { np0 = sm0; np1 = sm1; }
  WS_F(OFF_PATH)[2*i]   = np0;
  WS_F(OFF_PATH)[2*i+1] = np1;
  outp[2*i]   = np0;
  outp[2*i+1] = np1;
}

// ---------------- host launch ----------------

extern "C" void kernel_launch(void* const* d_in, const int* in_sizes, int n_in,
                              void* d_out, int out_size, void* d_ws, size_t ws_size,
                              hipStream_t stream) {
  const float* path  = (const float*)d_in[0];
  const float* freep = (const float*)d_in[1];
  const float* collp = (const float*)d_in[2];
  const int*   ei    = (const int*)d_in[4];
  const float* ncw1  = (const float*)d_in[6];
  const float* ncb1  = (const float*)d_in[7];
  const float* gamma = (const float*)d_in[8];
  const float* beta  = (const float*)d_in[9];
  const float* ncw2  = (const float*)d_in[10];
  const float* ncb2  = (const float*)d_in[11];
  const float* m0w1  = (const float*)d_in[12];
  const float* m0b1  = (const float*)d_in[13];
  const float* m0w2  = (const float*)d_in[14];
  const float* m0b2  = (const float*)d_in[15];
  const float* m1w1  = (const float*)d_in[16];
  const float* m1b1  = (const float*)d_in[17];
  const float* m1w2  = (const float*)d_in[18];
  const float* m1b2  = (const float*)d_in[19];
  const float* snw   = (const float*)d_in[20];
  const float* snb   = (const float*)d_in[21];
  char* ws = (char*)d_ws;

  k_init   <<<HSIZE/256, 256, 0, stream>>>(ws, path);
  k_cand   <<<(NCND+255)/256, 256, 0, stream>>>(ws, freep, collp, ncw1, ncb1);
  k_wprep  <<<1, 1024, 0, stream>>>(ws, m0w1, m0b1, ncw1, ncb1, ncw2, ncb2);
  k_edges  <<<(NEDGE+255)/256, 256, 0, stream>>>(ws, ei);
  k_hist   <<<(NCND+255)/256, 256, 0, stream>>>(ws);
  k_scan   <<<1, 256, 0, stream>>>(ws);
  k_scatter<<<(NCND+255)/256, 256, 0, stream>>>(ws);

  for (int l = 0; l < NLOOP; l++) {
    k_knng <<<PN/4 + 1, 256, 0, stream>>>(ws, ncw1, gamma, beta);
    k_loopB<<<(PN*KK + E0CAP + 255)/256, 256, 0, stream>>>(ws, ncw1, gamma, beta);
    k_loopC<<<2, 256, 0, stream>>>(ws, ncw1, gamma, beta, ncw2, ncb2,
                                   m0w2, m0b2, m1w1, m1b1, m1w2, m1b2,
                                   snw, snb, (float*)d_out);
  }
}

// Round 4
// 1734.854 us; speedup vs baseline: 2.1303x; 1.0027x over previous
//
#include <hip/hip_runtime.h>
#include <stdint.h>

// Problem constants (fixed by setup_inputs)
#define PN     512
#define NFREE  50000
#define NCND   100000
#define NNODE  100512
#define NEDGE  300000
#define KK     10
#define NLOOP  5
#define EPSV   1e-5f

#define GRID   128
#define NCELL  (GRID*GRID)

#define HSIZE  (1u<<19)
#define HMASK  (HSIZE-1)
#define E0CAP  4096
#define EMPTYK 0xFFFFFFFFFFFFFFFFull

// workspace layout (bytes) — total ~7.4 MB
#define OFF_HASH    ((size_t)0)
#define OFF_CPOS    (OFF_HASH    + (size_t)HSIZE*8)
#define OFF_CSQ     (OFF_CPOS    + 800000)
#define OFF_SCND    (OFF_CSQ     + 400000)               // float4/cand, cell-sorted
#define OFF_CSTART  (OFF_SCND    + 1600000)              // NCELL+1 ints
#define OFF_COFS    (OFF_CSTART  + 65600)
#define OFF_MNMX    (OFF_COFS    + 65600)
#define OFF_SUMC    (OFF_MNMX    + 64)
#define OFF_SUMC2   (OFF_SUMC    + 128)
#define OFF_MEAN    (OFF_SUMC2   + 128)
#define OFF_RSTD    (OFF_MEAN    + 128)
#define OFF_WCU     (OFF_RSTD    + 128)
#define OFF_WCV     (OFF_WCU     + 4096)
#define OFF_BU      (OFF_WCV     + 4096)
#define OFF_BV      (OFF_BU      + 128)
#define OFF_CPATH   (OFF_BV      + 128)
#define OFF_CFREE   (OFF_CPATH   + 128)
#define OFF_CCOL    (OFF_CFREE   + 128)
#define OFF_PATH    (OFF_CCOL    + 128)
#define OFF_UPATH   (OFF_PATH    + 4096)
#define OFF_VDST    (OFF_UPATH   + 65536)
#define OFF_SBUF    (OFF_VDST    + 65536)
#define OFF_E0S     (OFF_SBUF    + 65536)
#define OFF_E0D     (OFF_E0S     + (size_t)E0CAP*4)
#define OFF_DEG0    (OFF_E0D     + (size_t)E0CAP*4)
#define OFF_E0C     (OFF_DEG0    + 2048)
#define OFF_KSRC    (OFF_E0C     + 64)
#define OFF_KKEEP   (OFF_KSRC    + (size_t)PN*KK*4)
#define OFF_E0START (OFF_KKEEP   + (size_t)PN*KK*4)      // 513 ints (pad 2112)
#define OFF_E0OFS   (OFF_E0START + 2112)                 // 512 ints
#define OFF_E0CSRS  (OFF_E0OFS   + 2048)                 // E0CAP ints

#define WS_F(o)  ((float*)(ws + (o)))
#define WS_I(o)  ((int*)(ws + (o)))
#define WS_U(o)  ((unsigned*)(ws + (o)))
#define WS_H(o)  ((unsigned long long*)(ws + (o)))

__device__ __forceinline__ bool lexless(float da, int ia, float db, int ib) {
  return (da < db) || (da == db && ia < ib);
}

__device__ __forceinline__ uint32_t hslot(unsigned long long key) {
  return (uint32_t)((key * 0x9E3779B97F4A7C15ull) >> 40) & HMASK;
}

// monotone float<->uint order encoding (for atomicMin/Max on floats)
__device__ __forceinline__ unsigned encf(float f) {
  unsigned u = __float_as_uint(f);
  return (u & 0x80000000u) ? ~u : (u | 0x80000000u);
}
__device__ __forceinline__ float decf(unsigned u) {
  return (u & 0x80000000u) ? __uint_as_float(u & 0x7FFFFFFFu) : __uint_as_float(~u);
}

#define INSERT10(d2v, jv)                                                  \
  if (lexless((d2v), (jv), bd[9], bi[9])) {                                \
    bool placed = false;                                                   \
    _Pragma("unroll")                                                      \
    for (int k = 9; k > 0; k--) {                                          \
      bool shift = !placed && lexless((d2v), (jv), bd[k-1], bi[k-1]);      \
      bool here  = !placed && !shift;                                      \
      if (here)       { bd[k] = (d2v); bi[k] = (jv); placed = true; }      \
      else if (shift) { bd[k] = bd[k-1]; bi[k] = bi[k-1]; }                \
    }                                                                      \
    if (!placed) { bd[0] = (d2v); bi[0] = (jv); }                          \
  }

// ---------------- setup kernels (once per launch) ----------------

__global__ __launch_bounds__(256) void k_init(char* __restrict__ ws,
                                              const float* __restrict__ path_in) {
  unsigned i = blockIdx.x * 256u + threadIdx.x;       // grid = HSIZE/256
  WS_H(OFF_HASH)[i] = EMPTYK;
  if (i < NCELL+1) WS_I(OFF_CSTART)[i] = 0;
  if (i < 1024) WS_F(OFF_PATH)[i] = path_in[i];
  if (i < 512)  WS_I(OFF_DEG0)[i] = 0;
  if (i < 32) { WS_F(OFF_SUMC)[i] = 0.f; WS_F(OFF_SUMC2)[i] = 0.f; }
  if (i < 4)  WS_U(OFF_MNMX)[i] = (i & 1) ? 0u : 0xFFFFFFFFu;
  if (i == 0)   *WS_I(OFF_E0C) = 0;
}

// candidate positions, norms, BN partial sums, bbox min/max
__global__ __launch_bounds__(256) void k_cand(char* __restrict__ ws,
    const float* __restrict__ freep, const float* __restrict__ collp,
    const float* __restrict__ ncw1, const float* __restrict__ ncb1) {
  __shared__ float ls[64];
  __shared__ unsigned mm[4];
  int tid = threadIdx.x;
  if (tid < 64) ls[tid] = 0.f;
  if (tid < 4)  mm[tid] = (tid & 1) ? 0u : 0xFFFFFFFFu;
  __syncthreads();
  int j = blockIdx.x * 256 + tid;
  float c0 = 0.f, c1 = 0.f;
  bool valid = (j < NCND);
  if (valid) {
    if (j < NFREE) { c0 = freep[2*j];          c1 = freep[2*j+1]; }
    else           { c0 = collp[2*(j-NFREE)];  c1 = collp[2*(j-NFREE)+1]; }
    WS_F(OFF_CPOS)[2*j] = c0; WS_F(OFF_CPOS)[2*j+1] = c1;
    WS_F(OFF_CSQ)[j] = c0*c0 + c1*c1;
    atomicMin(&mm[0], encf(c0)); atomicMax(&mm[1], encf(c0));
    atomicMin(&mm[2], encf(c1)); atomicMax(&mm[3], encf(c1));
  }
  for (int ff = 0; ff < 32; ff++) {
    int f = (tid + ff) & 31;
    if (valid) {
      float cls = (j < NFREE) ? (ncw1[96+f] + ncb1[f]) : (ncw1[128+f] + ncb1[f]);
      float h = fmaf(c1, ncw1[32+f], fmaf(c0, ncw1[f], cls));
      atomicAdd(&ls[f], h);
      atomicAdd(&ls[32+f], h*h);
    }
  }
  __syncthreads();
  if (tid < 32) {
    atomicAdd(&WS_F(OFF_SUMC)[tid],  ls[tid]);
    atomicAdd(&WS_F(OFF_SUMC2)[tid], ls[32+tid]);
  }
  if (tid < 4) {
    if (tid & 1) atomicMax(&WS_U(OFF_MNMX)[tid], mm[tid]);
    else         atomicMin(&WS_U(OFF_MNMX)[tid], mm[tid]);
  }
}

// combined weights: Wcu = ncW2·(W1a+W1b), Wcv = ncW2·(W1c−W1a), biases, class consts
__global__ __launch_bounds__(1024) void k_wprep(char* __restrict__ ws,
    const float* __restrict__ m0w1, const float* __restrict__ m0b1,
    const float* __restrict__ ncw1, const float* __restrict__ ncb1,
    const float* __restrict__ ncw2, const float* __restrict__ ncb2) {
  __shared__ float Wu[1024], Wv[1024];
  int tid = threadIdx.x, k = tid >> 5, g = tid & 31;
  float a = m0w1[k*32+g], b = m0w1[(k+32)*32+g], c = m0w1[(k+64)*32+g];
  Wu[tid] = a + b;  Wv[tid] = c - a;
  __syncthreads();
  float au = 0.f, av = 0.f;
  #pragma unroll
  for (int f = 0; f < 32; f++) {
    float w2 = ncw2[k*32+f];
    au = fmaf(w2, Wu[f*32+g], au);
    av = fmaf(w2, Wv[f*32+g], av);
  }
  WS_F(OFF_WCU)[tid] = au;  WS_F(OFF_WCV)[tid] = av;
  if (tid < 32) {
    float bu = 0.f, bv = 0.f;
    #pragma unroll
    for (int f = 0; f < 32; f++) {
      bu = fmaf(ncb2[f], Wu[f*32+tid], bu);
      bv = fmaf(ncb2[f], Wv[f*32+tid], bv);
    }
    WS_F(OFF_BU)[tid] = bu;
    WS_F(OFF_BV)[tid] = bv + m0b1[tid];
    WS_F(OFF_CPATH)[tid] = ncw1[64+tid]  + ncb1[tid];
    WS_F(OFF_CFREE)[tid] = ncw1[96+tid]  + ncb1[tid];
    WS_F(OFF_CCOL)[tid]  = ncw1[128+tid] + ncb1[tid];
  }
}

// hash-insert fixed edges (dedupe); compact kept edges with dst<PN; deg0 histogram
__global__ __launch_bounds__(256) void k_edges(char* __restrict__ ws,
                                               const int* __restrict__ ei) {
  int e = blockIdx.x * 256 + threadIdx.x;
  if (e >= NEDGE) return;
  int src = ei[e], dst = ei[NEDGE + e];
  unsigned long long key = (unsigned long long)src * NNODE + (unsigned long long)dst;
  unsigned long long* hash = WS_H(OFF_HASH);
  uint32_t slot = hslot(key);
  bool win = false;
  for (;;) {
    unsigned long long prev = atomicCAS(&hash[slot], EMPTYK, key);
    if (prev == EMPTYK) { win = true; break; }
    if (prev == key)    { break; }
    slot = (slot + 1) & HMASK;
  }
  if (win && dst < PN) {
    int pos = atomicAdd(WS_I(OFF_E0C), 1);
    if (pos < E0CAP) {
      WS_I(OFF_E0S)[pos] = src;
      WS_I(OFF_E0D)[pos] = dst;
      atomicAdd(&WS_I(OFF_DEG0)[dst], 1);
    }
  }
}

// build per-dst CSR of fixed edges with dst<PN (~1528 entries, avg 3/dst)
__global__ __launch_bounds__(256) void k_csr(char* __restrict__ ws) {
  __shared__ int sc[512];
  int tid = threadIdx.x;
  sc[tid]     = WS_I(OFF_DEG0)[tid];
  sc[256+tid] = WS_I(OFF_DEG0)[256+tid];
  __syncthreads();
  if (tid == 0) {                     // one-time serial scan of 512 — fine
    int run = 0;
    for (int i = 0; i < 512; i++) { int c = sc[i]; sc[i] = run; run += c; }
    WS_I(OFF_E0START)[512] = run;
  }
  __syncthreads();
  WS_I(OFF_E0START)[tid]     = sc[tid];
  WS_I(OFF_E0START)[256+tid] = sc[256+tid];
  WS_I(OFF_E0OFS)[tid]       = sc[tid];
  WS_I(OFF_E0OFS)[256+tid]   = sc[256+tid];
  __syncthreads();
  int n = *WS_I(OFF_E0C); if (n > E0CAP) n = E0CAP;
  for (int e = tid; e < n; e += 256) {
    int dst = WS_I(OFF_E0D)[e];
    int pos = atomicAdd(&WS_I(OFF_E0OFS)[dst], 1);
    WS_I(OFF_E0CSRS)[pos] = WS_I(OFF_E0S)[e];
  }
}

// grid histogram over candidate cells
__global__ __launch_bounds__(256) void k_hist(char* __restrict__ ws) {
  int j = blockIdx.x * 256 + threadIdx.x;
  if (j >= NCND) return;
  const unsigned* mnmx = WS_U(OFF_MNMX);
  float xmin = decf(mnmx[0]), xmax = decf(mnmx[1]);
  float ymin = decf(mnmx[2]), ymax = decf(mnmx[3]);
  float ivx = (float)GRID / ((xmax - xmin) * 1.000001f + 1e-30f);
  float ivy = (float)GRID / ((ymax - ymin) * 1.000001f + 1e-30f);
  float c0 = WS_F(OFF_CPOS)[2*j], c1 = WS_F(OFF_CPOS)[2*j+1];
  int cx = min(GRID-1, max(0, (int)((c0 - xmin) * ivx)));
  int cy = min(GRID-1, max(0, (int)((c1 - ymin) * ivy)));
  atomicAdd(&WS_I(OFF_CSTART)[cy*GRID + cx], 1);
}

// exclusive scan of cell counts (single block)
__global__ __launch_bounds__(256) void k_scan(char* __restrict__ ws) {
  __shared__ int part[256];
  int tid = threadIdx.x;
  int* cnt = WS_I(OFF_CSTART);
  int base = tid * (NCELL/256);
  int sum = 0;
  for (int k = 0; k < NCELL/256; k++) sum += cnt[base+k];
  part[tid] = sum;
  __syncthreads();
  for (int off = 1; off < 256; off <<= 1) {
    int t = (tid >= off) ? part[tid - off] : 0;
    __syncthreads();
    part[tid] += t;
    __syncthreads();
  }
  int run = part[tid] - sum;
  for (int k = 0; k < NCELL/256; k++) {
    int c = cnt[base+k];
    cnt[base+k] = run;
    WS_I(OFF_COFS)[base+k] = run;
    run += c;
  }
  if (tid == 255) cnt[NCELL] = run;
}

// scatter candidates into cell-sorted float4 array (x, y, |c|^2, idx)
__global__ __launch_bounds__(256) void k_scatter(char* __restrict__ ws) {
  int j = blockIdx.x * 256 + threadIdx.x;
  if (j >= NCND) return;
  const unsigned* mnmx = WS_U(OFF_MNMX);
  float xmin = decf(mnmx[0]), xmax = decf(mnmx[1]);
  float ymin = decf(mnmx[2]), ymax = decf(mnmx[3]);
  float ivx = (float)GRID / ((xmax - xmin) * 1.000001f + 1e-30f);
  float ivy = (float)GRID / ((ymax - ymin) * 1.000001f + 1e-30f);
  float c0 = WS_F(OFF_CPOS)[2*j], c1 = WS_F(OFF_CPOS)[2*j+1];
  int cx = min(GRID-1, max(0, (int)((c0 - xmin) * ivx)));
  int cy = min(GRID-1, max(0, (int)((c1 - ymin) * ivy)));
  int pos = atomicAdd(&WS_I(OFF_COFS)[cy*GRID + cx], 1);
  ((float4*)(ws + OFF_SCND))[pos] =
      make_float4(c0, c1, WS_F(OFF_CSQ)[j], __int_as_float(j));
}

// ---------------- per-loop kernels ----------------

// non-destructive wave top-10 pop-merge: refreshes cur10d, lane r stores r-th idx
#define MERGEPOP() do {                                                    \
    float cd[10]; int ci[10];                                              \
    _Pragma("unroll")                                                      \
    for (int k = 0; k < 10; k++) { cd[k] = bd[k]; ci[k] = bi[k]; }         \
    _Pragma("unroll")                                                      \
    for (int r = 0; r < 10; r++) {                                         \
      float md = cd[0]; int mi = ci[0];                                    \
      _Pragma("unroll")                                                    \
      for (int off = 32; off >= 1; off >>= 1) {                            \
        float od = __shfl_xor(md, off);                                    \
        int   oi = __shfl_xor(mi, off);                                    \
        if (lexless(od, oi, md, mi)) { md = od; mi = oi; }                 \
      }                                                                    \
      bool win = (cd[0] == md) && (ci[0] == mi);                           \
      if (win) {                                                           \
        _Pragma("unroll")                                                  \
        for (int k = 0; k < 9; k++) { cd[k] = cd[k+1]; ci[k] = ci[k+1]; }  \
        cd[9] = 3.4e38f; ci[9] = 0x7FFFFFFF;                               \
      }                                                                    \
      if (lane == r) selIdx = mi;                                          \
      cur10d = md;                                                         \
    }                                                                      \
  } while (0)

// blocks 0..127: one wave per path node — grid-kNN (lane-parallel rings) +
// CSR dedup + KSRC/KKEEP.  block 128: BN stats + u/v + zero SBUF.
__global__ __launch_bounds__(256) void k_knng(char* __restrict__ ws,
    const float* __restrict__ ncw1, const float* __restrict__ gamma,
    const float* __restrict__ beta) {
  __shared__ float ps[128];
  int tid = threadIdx.x, b = blockIdx.x;
  float* pathb = WS_F(OFF_PATH);

  if (b < PN/4) {
    int lane = tid & 63, wave = tid >> 6;
    int node = (b << 2) + wave;
    const float4* scnd = (const float4*)(ws + OFF_SCND);
    const int* cst = WS_I(OFF_CSTART);
    const unsigned* mnmx = WS_U(OFF_MNMX);
    float xmin = decf(mnmx[0]), xmax = decf(mnmx[1]);
    float ymin = decf(mnmx[2]), ymax = decf(mnmx[3]);
    float spx = (xmax - xmin) * 1.000001f + 1e-30f;
    float spy = (ymax - ymin) * 1.000001f + 1e-30f;
    float ivx = (float)GRID / spx, ivy = (float)GRID / spy;
    float cwmin = fminf(spx, spy) * (1.0f / GRID);
    float p0 = pathb[2*node], p1 = pathb[2*node+1];
    float psq = p0*p0 + p1*p1;
    int cx = min(GRID-1, max(0, (int)((p0 - xmin) * ivx)));
    int cy = min(GRID-1, max(0, (int)((p1 - ymin) * ivy)));

    float bd[10]; int bi[10];
    #pragma unroll
    for (int k = 0; k < 10; k++) { bd[k] = 3.4e38f; bi[k] = 0x7FFFFFFF; }
    float cur10d = 3.4e38f;
    int selIdx = 0x7FFFFFFF;

    // ring 0: all 64 lanes cooperatively scan the home cell
    {
      int c = cy * GRID + cx;
      int s = cst[c], e = cst[c+1];
      for (int t = s + lane; t < e; t += 64) {
        float4 q = scnd[t];
        float d2 = (psq + q.z) - 2.f * fmaf(p1, q.y, p0 * q.x);
        int j = __float_as_int(q.w);
        INSERT10(d2, j);
      }
    }
    MERGEPOP();

    // rings rho>=1: one LANE per ring cell — parallel bound-loads, no serial
    // empty-cell walk (the R3 straggler: tail nodes scanned ~300 cells serially)
    for (int rho = 1; rho < GRID; rho++) {
      float dmin = (float)(rho - 1) * cwmin;
      if (dmin * dmin > cur10d) break;        // exact conservative prune
      int r2 = 2 * rho, ncells = 8 * rho;
      for (int base = 0; base < ncells; base += 64) {
        int e = base + lane;
        if (e < ncells) {
          int o = e, xx, yy;
          if      (o < r2)   {              xx = cx - rho + o; yy = cy - rho; }
          else if (o < 2*r2) { o -= r2;     xx = cx + rho;     yy = cy - rho + o; }
          else if (o < 3*r2) { o -= 2*r2;   xx = cx + rho - o; yy = cy + rho; }
          else               { o -= 3*r2;   xx = cx - rho;     yy = cy + rho - o; }
          if (xx >= 0 && xx < GRID && yy >= 0 && yy < GRID) {
            int c = yy * GRID + xx;
            int s = cst[c], en = cst[c+1];
            for (int t = s; t < en; t++) {
              float4 q = scnd[t];
              float d2 = (psq + q.z) - 2.f * fmaf(p1, q.y, p0 * q.x);
              int j = __float_as_int(q.w);
              INSERT10(d2, j);
            }
          }
        }
      }
      MERGEPOP();
    }

    // lanes 0..9 hold the rank-r neighbor; dedup vs fixed edges via tiny CSR
    if (lane < KK) {
      int srcg = selIdx + PN;
      int s = WS_I(OFF_E0START)[node], e = WS_I(OFF_E0START)[node+1];
      int keep = 1;
      for (int t = s; t < e; t++)
        if (WS_I(OFF_E0CSRS)[t] == srcg) { keep = 0; break; }
      WS_I(OFF_KSRC)[node*KK+lane]  = srcg;
      WS_I(OFF_KKEEP)[node*KK+lane] = keep;
    }
  } else {
    // ---- BN stats over path rows (cand part precomputed) ----
    if (tid < 64) ps[tid] = 0.f;
    __syncthreads();
    const float* cpath = WS_F(OFF_CPATH);
    for (int r = tid; r < PN; r += 256) {
      float p0 = pathb[2*r], p1 = pathb[2*r+1];
      for (int ff = 0; ff < 32; ff++) {
        int f = (tid + ff) & 31;
        float h = fmaf(p1, ncw1[32+f], fmaf(p0, ncw1[f], cpath[f]));
        atomicAdd(&ps[f], h);
        atomicAdd(&ps[32+f], h*h);
      }
    }
    __syncthreads();
    if (tid < 32) {
      float mean = (WS_F(OFF_SUMC)[tid]  + ps[tid])    * (1.f / NNODE);
      float ex2  = (WS_F(OFF_SUMC2)[tid] + ps[32+tid]) * (1.f / NNODE);
      float var  = ex2 - mean * mean;
      float rs   = 1.0f / sqrtf(var + EPSV);
      WS_F(OFF_MEAN)[tid] = mean; WS_F(OFF_RSTD)[tid] = rs;
      ps[64+tid] = mean; ps[96+tid] = rs;
    }
    __syncthreads();
    // ---- u/v for all 512 path nodes ----
    const float* wcu = WS_F(OFF_WCU); const float* wcv = WS_F(OFF_WCV);
    const float* bu  = WS_F(OFF_BU);  const float* bv  = WS_F(OFF_BV);
    for (int i = tid; i < PN; i += 256) {
      float p0 = pathb[2*i], p1 = pathb[2*i+1];
      float xn[32];
      #pragma unroll
      for (int f = 0; f < 32; f++) {
        float h = fmaf(p1, ncw1[32+f], fmaf(p0, ncw1[f], cpath[f]));
        float t = (h - ps[64+f]) * ps[96+f];
        t = fmaf(t, gamma[f], beta[f]);
        xn[f] = t > 0.f ? t : 0.f;
      }
      for (int f = 0; f < 32; f++) {
        float au = bu[f], av = bv[f];
        #pragma unroll
        for (int k = 0; k < 32; k++) {
          au = fmaf(xn[k], wcu[k*32+f], au);
          av = fmaf(xn[k], wcv[k*32+f], av);
        }
        WS_F(OFF_UPATH)[i*32+f] = au;
        WS_F(OFF_VDST)[i*32+f]  = av;
      }
    }
    for (int i = tid; i < PN*32; i += 256) WS_F(OFF_SBUF)[i] = 0.f;
  }
}

// per-edge: r = relu(u[src]+v[dst]) accumulated into S[dst]
__global__ __launch_bounds__(256) void k_loopB(char* __restrict__ ws,
    const float* __restrict__ ncw1, const float* __restrict__ gamma,
    const float* __restrict__ beta) {
  int t = blockIdx.x * 256 + threadIdx.x;
  int src, dst;
  if (t < PN*KK) {
    dst = t / KK;
    src = WS_I(OFF_KSRC)[t];
    if (!WS_I(OFF_KKEEP)[t]) return;
  } else {
    int e = t - PN*KK;
    if (e >= *WS_I(OFF_E0C)) return;
    src = WS_I(OFF_E0S)[e];
    dst = WS_I(OFF_E0D)[e];
  }
  float u[32];
  if (src < PN) {
    const float4* up4 = (const float4*)&WS_F(OFF_UPATH)[src*32];
    #pragma unroll
    for (int q = 0; q < 8; q++) {
      float4 w = up4[q];
      u[4*q] = w.x; u[4*q+1] = w.y; u[4*q+2] = w.z; u[4*q+3] = w.w;
    }
  } else {
    int j = src - PN;
    float c0 = WS_F(OFF_CPOS)[2*j], c1 = WS_F(OFF_CPOS)[2*j+1];
    const float* cls = (j < NFREE) ? WS_F(OFF_CFREE) : WS_F(OFF_CCOL);
    const float* mean = WS_F(OFF_MEAN); const float* rstd = WS_F(OFF_RSTD);
    float xn[32];
    #pragma unroll
    for (int f = 0; f < 32; f++) {
      float h = fmaf(c1, ncw1[32+f], fmaf(c0, ncw1[f], cls[f]));
      float tt = (h - mean[f]) * rstd[f];
      tt = fmaf(tt, gamma[f], beta[f]);
      xn[f] = tt > 0.f ? tt : 0.f;
    }
    const float* wcu = WS_F(OFF_WCU); const float* bu = WS_F(OFF_BU);
    for (int f = 0; f < 32; f++) {
      float au = bu[f];
      #pragma unroll
      for (int k = 0; k < 32; k++) au = fmaf(xn[k], wcu[k*32+f], au);
      u[f] = au;
    }
  }
  const float* vd = &WS_F(OFF_VDST)[dst*32];
  float* sb = &WS_F(OFF_SBUF)[dst*32];
  #pragma unroll
  for (int f = 0; f < 32; f++) {
    float r = u[f] + vd[f];
    if (r > 0.f) atomicAdd(&sb[f], r);
  }
}

// epilogue per path node: out -> mp1 -> h = x + g -> smooth -> path update + d_out
__global__ __launch_bounds__(256) void k_loopC(char* __restrict__ ws,
    const float* __restrict__ ncw1, const float* __restrict__ gamma,
    const float* __restrict__ beta, const float* __restrict__ ncw2,
    const float* __restrict__ ncb2, const float* __restrict__ m0w2,
    const float* __restrict__ m0b2, const float* __restrict__ m1w1,
    const float* __restrict__ m1b1, const float* __restrict__ m1w2,
    const float* __restrict__ m1b2, const float* __restrict__ snw,
    const float* __restrict__ snb, float* __restrict__ outp) {
  int i = blockIdx.x * 256 + threadIdx.x;
  if (i >= PN) return;
  float s[32];
  #pragma unroll
  for (int f = 0; f < 32; f++) s[f] = WS_F(OFF_SBUF)[i*32+f];
  int deg = WS_I(OFF_DEG0)[i];
  #pragma unroll
  for (int k = 0; k < KK; k++) deg += WS_I(OFF_KKEEP)[i*KK+k];
  float fdeg = (float)deg;

  float o[32];
  for (int f = 0; f < 32; f++) {
    float acc = 0.f;
    #pragma unroll
    for (int k = 0; k < 32; k++) acc = fmaf(s[k], m0w2[k*32+f], acc);
    o[f] = fmaf(fdeg, m0b2[f], acc);
  }
  float t[32];
  for (int f = 0; f < 32; f++) {
    float acc = m1b1[f];
    #pragma unroll
    for (int k = 0; k < 32; k++) acc = fmaf(o[k], m1w1[k*32+f], acc);
    t[f] = acc > 0.f ? acc : 0.f;
  }
  float g[32];
  for (int f = 0; f < 32; f++) {
    float acc = m1b2[f];
    #pragma unroll
    for (int k = 0; k < 32; k++) acc = fmaf(t[k], m1w2[k*32+f], acc);
    g[f] = acc;
  }
  float p0 = WS_F(OFF_PATH)[2*i], p1 = WS_F(OFF_PATH)[2*i+1];
  const float* cpath = WS_F(OFF_CPATH);
  const float* mean = WS_F(OFF_MEAN); const float* rstd = WS_F(OFF_RSTD);
  float xn[32];
  #pragma unroll
  for (int f = 0; f < 32; f++) {
    float h = fmaf(p1, ncw1[32+f], fmaf(p0, ncw1[f], cpath[f]));
    float tt = (h - mean[f]) * rstd[f];
    tt = fmaf(tt, gamma[f], beta[f]);
    xn[f] = tt > 0.f ? tt : 0.f;
  }
  float sm0 = snb[0], sm1 = snb[1];
  for (int f = 0; f < 32; f++) {
    float acc = ncb2[f];
    #pragma unroll
    for (int k = 0; k < 32; k++) acc = fmaf(xn[k], ncw2[k*32+f], acc);
    float h = acc + g[f];
    sm0 = fmaf(h, snw[2*f],   sm0);
    sm1 = fmaf(h, snw[2*f+1], sm1);
  }
  float np0, np1;
  if (i == 0 || i == PN-1) { np0 = p0; np1 = p1; }
  else                     { np0 = sm0; np1 = sm1; }
  WS_F(OFF_PATH)[2*i]   = np0;
  WS_F(OFF_PATH)[2*i+1] = np1;
  outp[2*i]   = np0;
  outp[2*i+1] = np1;
}

// ---------------- host launch ----------------

extern "C" void kernel_launch(void* const* d_in, const int* in_sizes, int n_in,
                              void* d_out, int out_size, void* d_ws, size_t ws_size,
                              hipStream_t stream) {
  const float* path  = (const float*)d_in[0];
  const float* freep = (const float*)d_in[1];
  const float* collp = (const float*)d_in[2];
  const int*   ei    = (const int*)d_in[4];
  const float* ncw1  = (const float*)d_in[6];
  const float* ncb1  = (const float*)d_in[7];
  const float* gamma = (const float*)d_in[8];
  const float* beta  = (const float*)d_in[9];
  const float* ncw2  = (const float*)d_in[10];
  const float* ncb2  = (const float*)d_in[11];
  const float* m0w1  = (const float*)d_in[12];
  const float* m0b1  = (const float*)d_in[13];
  const float* m0w2  = (const float*)d_in[14];
  const float* m0b2  = (const float*)d_in[15];
  const float* m1w1  = (const float*)d_in[16];
  const float* m1b1  = (const float*)d_in[17];
  const float* m1w2  = (const float*)d_in[18];
  const float* m1b2  = (const float*)d_in[19];
  const float* snw   = (const float*)d_in[20];
  const float* snb   = (const float*)d_in[21];
  char* ws = (char*)d_ws;

  k_init   <<<HSIZE/256, 256, 0, stream>>>(ws, path);
  k_cand   <<<(NCND+255)/256, 256, 0, stream>>>(ws, freep, collp, ncw1, ncb1);
  k_wprep  <<<1, 1024, 0, stream>>>(ws, m0w1, m0b1, ncw1, ncb1, ncw2, ncb2);
  k_edges  <<<(NEDGE+255)/256, 256, 0, stream>>>(ws, ei);
  k_csr    <<<1, 256, 0, stream>>>(ws);
  k_hist   <<<(NCND+255)/256, 256, 0, stream>>>(ws);
  k_scan   <<<1, 256, 0, stream>>>(ws);
  k_scatter<<<(NCND+255)/256, 256, 0, stream>>>(ws);

  for (int l = 0; l < NLOOP; l++) {
    k_knng <<<PN/4 + 1, 256, 0, stream>>>(ws, ncw1, gamma, beta);
    k_loopB<<<(PN*KK + E0CAP + 255)/256, 256, 0, stream>>>(ws, ncw1, gamma, beta);
    k_loopC<<<2, 256, 0, stream>>>(ws, ncw1, gamma, beta, ncw2, ncb2,
                                   m0w2, m0b2, m1w1, m1b1, m1w2, m1b2,
                                   snw, snb, (float*)d_out);
  }
}